// Round 3
// baseline (2501.925 us; speedup 1.0000x reference)
//
#include <hip/hip_runtime.h>
#include <hip/hip_bf16.h>
#include <hip/hip_fp16.h>

#define NN      50000
#define INDIM   128
#define HDIM    128      // HEADS*HEAD_DIM
#define EREAL   600000
#define ETOT    650000

typedef unsigned short u16;

__device__ __forceinline__ float h2f(u16 h) {
    __half v; __builtin_memcpy(&v, &h, 2); return __half2float(v);
}
__device__ __forceinline__ u16 f2h(float f) {
    __half v = __float2half(f);
    u16 u; __builtin_memcpy(&u, &v, 2); return u;
}
__device__ __forceinline__ void cvt8h(uint4 u, float* f) {
    f[0] = h2f(u.x & 0xffffu); f[1] = h2f(u.x >> 16);
    f[2] = h2f(u.y & 0xffffu); f[3] = h2f(u.y >> 16);
    f[4] = h2f(u.z & 0xffffu); f[5] = h2f(u.z >> 16);
    f[6] = h2f(u.w & 0xffffu); f[7] = h2f(u.w >> 16);
}

// ---------------------------------------------------------------------------
// Stage 1: Q/K/V projection (f32 in -> f16 out). 16 nodes per block.
// thread = colgroup (cg: 4 cols) x slot (2 nodes). x tile staged in LDS.
// W rows read as float4: 512B/row stream per matrix, L2-resident (64KB each).
// ---------------------------------------------------------------------------
__global__ __launch_bounds__(256) void qkv_proj(
    const float* __restrict__ x,
    const float* __restrict__ Wq, const float* __restrict__ bq,
    const float* __restrict__ Wk, const float* __restrict__ bk,
    const float* __restrict__ Wv, const float* __restrict__ bv,
    u16* __restrict__ Q, u16* __restrict__ K, u16* __restrict__ V)
{
    __shared__ float xs[16][INDIM];
    const int tid = threadIdx.x;
    const int nb  = blockIdx.x * 16;

    {   // stage x tile: 16x128 f32 = 512 float4s; each thread loads 2
        const float4* xsrc = reinterpret_cast<const float4*>(x + (size_t)nb * INDIM);
        float4 a = xsrc[tid];
        float4 b = xsrc[tid + 256];
        int r = tid >> 5, c = (tid << 2) & 127;
        xs[r][c] = a.x; xs[r][c+1] = a.y; xs[r][c+2] = a.z; xs[r][c+3] = a.w;
        xs[r+8][c] = b.x; xs[r+8][c+1] = b.y; xs[r+8][c+2] = b.z; xs[r+8][c+3] = b.w;
    }
    __syncthreads();

    const int cg   = tid & 31;       // column group: cols cg*4 .. cg*4+3
    const int slot = tid >> 5;       // 0..7 -> nodes slot*2, slot*2+1
    const int n0 = slot * 2, n1 = n0 + 1;

    float aq0[4] = {0,0,0,0}, aq1[4] = {0,0,0,0};
    float ak0[4] = {0,0,0,0}, ak1[4] = {0,0,0,0};
    float av0[4] = {0,0,0,0}, av1[4] = {0,0,0,0};

    for (int i = 0; i < INDIM; i++) {
        float4 fq = reinterpret_cast<const float4*>(Wq + i * HDIM)[cg];
        float4 fk = reinterpret_cast<const float4*>(Wk + i * HDIM)[cg];
        float4 fv = reinterpret_cast<const float4*>(Wv + i * HDIM)[cg];
        float x0 = xs[n0][i], x1 = xs[n1][i];
        aq0[0] += x0*fq.x; aq0[1] += x0*fq.y; aq0[2] += x0*fq.z; aq0[3] += x0*fq.w;
        aq1[0] += x1*fq.x; aq1[1] += x1*fq.y; aq1[2] += x1*fq.z; aq1[3] += x1*fq.w;
        ak0[0] += x0*fk.x; ak0[1] += x0*fk.y; ak0[2] += x0*fk.z; ak0[3] += x0*fk.w;
        ak1[0] += x1*fk.x; ak1[1] += x1*fk.y; ak1[2] += x1*fk.z; ak1[3] += x1*fk.w;
        av0[0] += x0*fv.x; av0[1] += x0*fv.y; av0[2] += x0*fv.z; av0[3] += x0*fv.w;
        av1[0] += x1*fv.x; av1[1] += x1*fv.y; av1[2] += x1*fv.z; av1[3] += x1*fv.w;
    }

    float4 bqa = reinterpret_cast<const float4*>(bq)[cg];
    float4 bka = reinterpret_cast<const float4*>(bk)[cg];
    float4 bva = reinterpret_cast<const float4*>(bv)[cg];

    ushort4 o;
    size_t r0 = (size_t)(nb + n0) * HDIM, r1 = (size_t)(nb + n1) * HDIM;
    o.x=f2h(aq0[0]+bqa.x); o.y=f2h(aq0[1]+bqa.y); o.z=f2h(aq0[2]+bqa.z); o.w=f2h(aq0[3]+bqa.w);
    reinterpret_cast<ushort4*>(Q + r0)[cg] = o;
    o.x=f2h(aq1[0]+bqa.x); o.y=f2h(aq1[1]+bqa.y); o.z=f2h(aq1[2]+bqa.z); o.w=f2h(aq1[3]+bqa.w);
    reinterpret_cast<ushort4*>(Q + r1)[cg] = o;
    o.x=f2h(ak0[0]+bka.x); o.y=f2h(ak0[1]+bka.y); o.z=f2h(ak0[2]+bka.z); o.w=f2h(ak0[3]+bka.w);
    reinterpret_cast<ushort4*>(K + r0)[cg] = o;
    o.x=f2h(ak1[0]+bka.x); o.y=f2h(ak1[1]+bka.y); o.z=f2h(ak1[2]+bka.z); o.w=f2h(ak1[3]+bka.w);
    reinterpret_cast<ushort4*>(K + r1)[cg] = o;
    o.x=f2h(av0[0]+bva.x); o.y=f2h(av0[1]+bva.y); o.z=f2h(av0[2]+bva.z); o.w=f2h(av0[3]+bva.w);
    reinterpret_cast<ushort4*>(V + r0)[cg] = o;
    o.x=f2h(av1[0]+bva.x); o.y=f2h(av1[1]+bva.y); o.z=f2h(av1[2]+bva.z); o.w=f2h(av1[3]+bva.w);
    reinterpret_cast<ushort4*>(V + r1)[cg] = o;
}

// ---------------------------------------------------------------------------
// Stage 2: per-edge score + scatter. 16 lanes per edge; lane covers 8 elems.
// Q/K/V are f16 (workspace); E tables are f32 (inputs).
// Head h = lane/2; dot completed with shfl_xor(p,1).
// ---------------------------------------------------------------------------
__global__ __launch_bounds__(256) void edge_scatter(
    const u16* __restrict__ Q, const u16* __restrict__ K, const u16* __restrict__ V,
    const float* __restrict__ Et, const float* __restrict__ Eft,
    const int* __restrict__ eattr, const int* __restrict__ esrc,
    const int* __restrict__ edst,
    float* __restrict__ wV, float* __restrict__ Z)
{
    const int g    = (blockIdx.x * 256 + threadIdx.x) >> 4;   // edge id
    const int lane = threadIdx.x & 15;
    if (g >= ETOT) return;

    const int src  = esrc[g];
    const int dest = edst[g];
    const float* erow = (g < EREAL) ? (Et + (size_t)eattr[g] * HDIM) : Eft;

    uint4 ku = *reinterpret_cast<const uint4*>(K + (size_t)src  * HDIM + lane * 8);
    uint4 qu = *reinterpret_cast<const uint4*>(Q + (size_t)dest * HDIM + lane * 8);
    float4 e0 = *reinterpret_cast<const float4*>(erow + lane * 8);
    float4 e1 = *reinterpret_cast<const float4*>(erow + lane * 8 + 4);

    float kf[8], qf[8];
    cvt8h(ku, kf); cvt8h(qu, qf);
    float p = kf[0]*qf[0]*e0.x + kf[1]*qf[1]*e0.y + kf[2]*qf[2]*e0.z + kf[3]*qf[3]*e0.w
            + kf[4]*qf[4]*e1.x + kf[5]*qf[5]*e1.y + kf[6]*qf[6]*e1.z + kf[7]*qf[7]*e1.w;
    p += __shfl_xor(p, 1);
    float s = fminf(fmaxf(p * 0.25f, -5.f), 5.f);   // scale = 1/sqrt(16)
    float sc = __expf(s);

    uint4 vu = *reinterpret_cast<const uint4*>(V + (size_t)src * HDIM + lane * 8);
    float vf[8]; cvt8h(vu, vf);
    float* wdst = wV + (size_t)dest * HDIM + lane * 8;
    #pragma unroll
    for (int j = 0; j < 8; j++) unsafeAtomicAdd(wdst + j, vf[j] * sc);
    if ((lane & 1) == 0) unsafeAtomicAdd(Z + (size_t)dest * 8 + (lane >> 1), sc);
}

// ---------------------------------------------------------------------------
// Stage 3: out = wV / (Z + 1e-6), f32 out. 4 elems/thread (4 | 16 same head).
// ---------------------------------------------------------------------------
__global__ __launch_bounds__(256) void finalize_k(
    const float* __restrict__ wV, const float* __restrict__ Z,
    float* __restrict__ out)
{
    int t = blockIdx.x * 256 + threadIdx.x;
    int base = t * 4;
    if (base >= NN * HDIM) return;
    float4 w = reinterpret_cast<const float4*>(wV)[t];
    int n = base >> 7;
    int h = (base & 127) >> 4;
    float inv = 1.0f / (Z[n * 8 + h] + 1e-6f);
    float4 o;
    o.x = w.x * inv; o.y = w.y * inv; o.z = w.z * inv; o.w = w.w * inv;
    reinterpret_cast<float4*>(out)[t] = o;
}

extern "C" void kernel_launch(void* const* d_in, const int* in_sizes, int n_in,
                              void* d_out, int out_size, void* d_ws, size_t ws_size,
                              hipStream_t stream)
{
    const float* x   = (const float*)d_in[0];
    const float* Wq  = (const float*)d_in[1];
    const float* bq  = (const float*)d_in[2];
    const float* Wk  = (const float*)d_in[3];
    const float* bk  = (const float*)d_in[4];
    const float* Wv  = (const float*)d_in[5];
    const float* bv  = (const float*)d_in[6];
    const float* Et  = (const float*)d_in[7];
    const float* Eft = (const float*)d_in[8];
    const int* eattr = (const int*)d_in[9];
    // d_in[10] = fake_edge_attr (all zeros, Ef_table has 1 row) -> unused
    const int* esrc  = (const int*)d_in[11];
    const int* edst  = (const int*)d_in[12];
    // d_in[13] = fake_edge_index -> unused by reference

    char* ws = (char*)d_ws;
    const size_t qkv_bytes = (size_t)NN * HDIM * sizeof(u16);   // 12.8 MB
    u16*   Q  = (u16*)(ws);
    u16*   K  = (u16*)(ws + qkv_bytes);
    u16*   V  = (u16*)(ws + 2 * qkv_bytes);
    float* wV = (float*)(ws + 3 * qkv_bytes);                    // 25.6 MB
    float* Z  = (float*)(ws + 3 * qkv_bytes + (size_t)NN * HDIM * sizeof(float));

    // zero accumulators (wV and Z are contiguous)
    hipMemsetAsync(wV, 0, (size_t)NN * HDIM * sizeof(float) + (size_t)NN * 8 * sizeof(float), stream);

    qkv_proj<<<NN / 16, 256, 0, stream>>>(x, Wq, bq, Wk, bk, Wv, bv, Q, K, V);
    edge_scatter<<<ETOT / 16, 256, 0, stream>>>(Q, K, V, Et, Eft, eattr, esrc, edst, wV, Z);
    finalize_k<<<NN * HDIM / 1024, 256, 0, stream>>>(wV, Z, (float*)d_out);
}

// Round 4
// 304.479 us; speedup vs baseline: 8.2171x; 8.2171x over previous
//
#include <hip/hip_runtime.h>
#include <hip/hip_bf16.h>
#include <hip/hip_fp16.h>

#define NN      50000
#define INDIM   128
#define HDIM    128      // HEADS*HEAD_DIM
#define EREAL   600000
#define ETOT    650000

typedef unsigned short u16;

__device__ __forceinline__ float h2f(unsigned int h) {
    __half v; u16 s = (u16)h; __builtin_memcpy(&v, &s, 2); return __half2float(v);
}
__device__ __forceinline__ u16 f2h(float f) {
    __half v = __float2half(f);
    u16 u; __builtin_memcpy(&u, &v, 2); return u;
}

// ---------------------------------------------------------------------------
// Stage 1: Q/K/V projection (f32 in -> f16 out). 16 nodes per block.
// (unchanged from verified round-3 kernel)
// ---------------------------------------------------------------------------
__global__ __launch_bounds__(256) void qkv_proj(
    const float* __restrict__ x,
    const float* __restrict__ Wq, const float* __restrict__ bq,
    const float* __restrict__ Wk, const float* __restrict__ bk,
    const float* __restrict__ Wv, const float* __restrict__ bv,
    u16* __restrict__ Q, u16* __restrict__ K, u16* __restrict__ V)
{
    __shared__ float xs[16][INDIM];
    const int tid = threadIdx.x;
    const int nb  = blockIdx.x * 16;

    {
        const float4* xsrc = reinterpret_cast<const float4*>(x + (size_t)nb * INDIM);
        float4 a = xsrc[tid];
        float4 b = xsrc[tid + 256];
        int r = tid >> 5, c = (tid << 2) & 127;
        xs[r][c] = a.x; xs[r][c+1] = a.y; xs[r][c+2] = a.z; xs[r][c+3] = a.w;
        xs[r+8][c] = b.x; xs[r+8][c+1] = b.y; xs[r+8][c+2] = b.z; xs[r+8][c+3] = b.w;
    }
    __syncthreads();

    const int cg   = tid & 31;
    const int slot = tid >> 5;
    const int n0 = slot * 2, n1 = n0 + 1;

    float aq0[4] = {0,0,0,0}, aq1[4] = {0,0,0,0};
    float ak0[4] = {0,0,0,0}, ak1[4] = {0,0,0,0};
    float av0[4] = {0,0,0,0}, av1[4] = {0,0,0,0};

    for (int i = 0; i < INDIM; i++) {
        float4 fq = reinterpret_cast<const float4*>(Wq + i * HDIM)[cg];
        float4 fk = reinterpret_cast<const float4*>(Wk + i * HDIM)[cg];
        float4 fv = reinterpret_cast<const float4*>(Wv + i * HDIM)[cg];
        float x0 = xs[n0][i], x1 = xs[n1][i];
        aq0[0] += x0*fq.x; aq0[1] += x0*fq.y; aq0[2] += x0*fq.z; aq0[3] += x0*fq.w;
        aq1[0] += x1*fq.x; aq1[1] += x1*fq.y; aq1[2] += x1*fq.z; aq1[3] += x1*fq.w;
        ak0[0] += x0*fk.x; ak0[1] += x0*fk.y; ak0[2] += x0*fk.z; ak0[3] += x0*fk.w;
        ak1[0] += x1*fk.x; ak1[1] += x1*fk.y; ak1[2] += x1*fk.z; ak1[3] += x1*fk.w;
        av0[0] += x0*fv.x; av0[1] += x0*fv.y; av0[2] += x0*fv.z; av0[3] += x0*fv.w;
        av1[0] += x1*fv.x; av1[1] += x1*fv.y; av1[2] += x1*fv.z; av1[3] += x1*fv.w;
    }

    float4 bqa = reinterpret_cast<const float4*>(bq)[cg];
    float4 bka = reinterpret_cast<const float4*>(bk)[cg];
    float4 bva = reinterpret_cast<const float4*>(bv)[cg];

    ushort4 o;
    size_t r0 = (size_t)(nb + n0) * HDIM, r1 = (size_t)(nb + n1) * HDIM;
    o.x=f2h(aq0[0]+bqa.x); o.y=f2h(aq0[1]+bqa.y); o.z=f2h(aq0[2]+bqa.z); o.w=f2h(aq0[3]+bqa.w);
    reinterpret_cast<ushort4*>(Q + r0)[cg] = o;
    o.x=f2h(aq1[0]+bqa.x); o.y=f2h(aq1[1]+bqa.y); o.z=f2h(aq1[2]+bqa.z); o.w=f2h(aq1[3]+bqa.w);
    reinterpret_cast<ushort4*>(Q + r1)[cg] = o;
    o.x=f2h(ak0[0]+bka.x); o.y=f2h(ak0[1]+bka.y); o.z=f2h(ak0[2]+bka.z); o.w=f2h(ak0[3]+bka.w);
    reinterpret_cast<ushort4*>(K + r0)[cg] = o;
    o.x=f2h(ak1[0]+bka.x); o.y=f2h(ak1[1]+bka.y); o.z=f2h(ak1[2]+bka.z); o.w=f2h(ak1[3]+bka.w);
    reinterpret_cast<ushort4*>(K + r1)[cg] = o;
    o.x=f2h(av0[0]+bva.x); o.y=f2h(av0[1]+bva.y); o.z=f2h(av0[2]+bva.z); o.w=f2h(av0[3]+bva.w);
    reinterpret_cast<ushort4*>(V + r0)[cg] = o;
    o.x=f2h(av1[0]+bva.x); o.y=f2h(av1[1]+bva.y); o.z=f2h(av1[2]+bva.z); o.w=f2h(av1[3]+bva.w);
    reinterpret_cast<ushort4*>(V + r1)[cg] = o;
}

// ---------------------------------------------------------------------------
// CSR build: histogram -> hierarchical exclusive scan -> scatter
// ---------------------------------------------------------------------------
__global__ __launch_bounds__(256) void hist_k(
    const int* __restrict__ edst, int* __restrict__ counts)
{
    int t = blockIdx.x * 256 + threadIdx.x;
    if (t < ETOT) atomicAdd(&counts[edst[t]], 1);
}

// scan_a: per-block (256 elems) total
__global__ __launch_bounds__(256) void scan_a(
    const int* __restrict__ counts, int* __restrict__ blocksum)
{
    __shared__ int s[256];
    int t = threadIdx.x, b = blockIdx.x;
    int i = b * 256 + t;
    int v = (i < NN) ? counts[i] : 0;
    s[t] = v; __syncthreads();
    for (int d = 128; d > 0; d >>= 1) {
        if (t < d) s[t] += s[t + d];
        __syncthreads();
    }
    if (t == 0) blocksum[b] = s[0];
}

// scan_b: exclusive scan of 196 block sums (single block)
__global__ __launch_bounds__(256) void scan_b(
    const int* __restrict__ blocksum, int* __restrict__ blockoffs,
    int* __restrict__ offs)
{
    __shared__ int s[256];
    int t = threadIdx.x;
    int nb = (NN + 255) / 256;                 // 196
    int v = (t < nb) ? blocksum[t] : 0;
    s[t] = v; __syncthreads();
    for (int d = 1; d < 256; d <<= 1) {
        int add = (t >= d) ? s[t - d] : 0;
        __syncthreads();
        s[t] += add;
        __syncthreads();
    }
    if (t < nb) blockoffs[t] = s[t] - v;       // exclusive
    if (t == 0) offs[NN] = ETOT;
}

// scan_c: per-block exclusive scan + block offset -> offs & cursor
__global__ __launch_bounds__(256) void scan_c(
    const int* __restrict__ counts, const int* __restrict__ blockoffs,
    int* __restrict__ offs, int* __restrict__ cursor)
{
    __shared__ int s[256];
    int t = threadIdx.x, b = blockIdx.x;
    int i = b * 256 + t;
    int v = (i < NN) ? counts[i] : 0;
    s[t] = v; __syncthreads();
    for (int d = 1; d < 256; d <<= 1) {
        int add = (t >= d) ? s[t - d] : 0;
        __syncthreads();
        s[t] += add;
        __syncthreads();
    }
    if (i < NN) {
        int off = blockoffs[b] + s[t] - v;     // exclusive
        offs[i] = off;
        cursor[i] = off;
    }
}

__global__ __launch_bounds__(256) void scatter_k(
    const int* __restrict__ esrc, const int* __restrict__ edst,
    const int* __restrict__ eattr,
    int* __restrict__ cursor, int* __restrict__ sorted)
{
    int t = blockIdx.x * 256 + threadIdx.x;
    if (t >= ETOT) return;
    int dest = edst[t];
    int attr = (t < EREAL) ? eattr[t] : 16;    // 16 = fake-edge row
    int pos = atomicAdd(&cursor[dest], 1);
    sorted[pos] = esrc[t] | (attr << 20);
}

// ---------------------------------------------------------------------------
// Stage 2: gather-reduce. One wave per dest node; lane covers 2 elems.
// Head = 16 elems = 8 lanes; dot reduced with 3 shfl_xor. No atomics.
// ---------------------------------------------------------------------------
__global__ __launch_bounds__(256) void gather_reduce(
    const u16* __restrict__ Q, const u16* __restrict__ K, const u16* __restrict__ V,
    const float* __restrict__ Et, const float* __restrict__ Eft,
    const int* __restrict__ offs, const int* __restrict__ sorted,
    float* __restrict__ out)
{
    const int lane = threadIdx.x & 63;
    int n = blockIdx.x * 4 + (threadIdx.x >> 6);
    n = __builtin_amdgcn_readfirstlane(n);     // force SGPR -> s_load path

    const unsigned int* Qp = reinterpret_cast<const unsigned int*>(Q);
    const unsigned int* Kp = reinterpret_cast<const unsigned int*>(K);
    const unsigned int* Vp = reinterpret_cast<const unsigned int*>(V);

    unsigned int qu = Qp[(size_t)n * 64 + lane];
    const float q0 = h2f(qu & 0xffffu), q1 = h2f(qu >> 16);

    float accx = 0.f, accy = 0.f, zacc = 0.f;
    const int base = offs[n], end = offs[n + 1];

    for (int i = base; i < end; ++i) {
        int rec  = sorted[i];
        int src  = rec & 0xFFFFF;
        int attr = rec >> 20;
        unsigned int ku = Kp[(size_t)src * 64 + lane];
        unsigned int vu = Vp[(size_t)src * 64 + lane];
        const float* ep = (attr < 16) ? (Et + attr * HDIM) : Eft;
        float2 e = *reinterpret_cast<const float2*>(ep + 2 * lane);

        float p = h2f(ku & 0xffffu) * q0 * e.x + h2f(ku >> 16) * q1 * e.y;
        p += __shfl_xor(p, 1);
        p += __shfl_xor(p, 2);
        p += __shfl_xor(p, 4);
        float s  = fminf(fmaxf(p * 0.25f, -5.f), 5.f);
        float sc = __expf(s);

        accx += h2f(vu & 0xffffu) * sc;
        accy += h2f(vu >> 16) * sc;
        zacc += sc;
    }

    float inv = 1.f / (zacc + 1e-6f);
    float2 o; o.x = accx * inv; o.y = accy * inv;
    *reinterpret_cast<float2*>(out + (size_t)n * HDIM + 2 * lane) = o;
}

extern "C" void kernel_launch(void* const* d_in, const int* in_sizes, int n_in,
                              void* d_out, int out_size, void* d_ws, size_t ws_size,
                              hipStream_t stream)
{
    const float* x   = (const float*)d_in[0];
    const float* Wq  = (const float*)d_in[1];
    const float* bq  = (const float*)d_in[2];
    const float* Wk  = (const float*)d_in[3];
    const float* bk  = (const float*)d_in[4];
    const float* Wv  = (const float*)d_in[5];
    const float* bv  = (const float*)d_in[6];
    const float* Et  = (const float*)d_in[7];
    const float* Eft = (const float*)d_in[8];
    const int* eattr = (const int*)d_in[9];
    const int* esrc  = (const int*)d_in[11];
    const int* edst  = (const int*)d_in[12];

    char* ws = (char*)d_ws;
    const size_t qkv_bytes = (size_t)NN * HDIM * sizeof(u16);       // 12,800,000
    u16* Q = (u16*)(ws);
    u16* K = (u16*)(ws + qkv_bytes);
    u16* V = (u16*)(ws + 2 * qkv_bytes);
    size_t off = 3 * qkv_bytes;                                     // 38,400,000
    int* offs      = (int*)(ws + off); off += ((NN + 1) * 4 + 12) & ~15ull;
    int* cursor    = (int*)(ws + off); off += (size_t)NN * 4;
    int* counts    = (int*)(ws + off); off += (size_t)NN * 4;
    int* blocksum  = (int*)(ws + off); off += 1024;
    int* blockoffs = (int*)(ws + off); off += 1024;
    int* sorted    = (int*)(ws + off);                              // 2.6 MB

    const int NB = (NN + 255) / 256;       // 196
    const int EB = (ETOT + 255) / 256;     // 2540

    hipMemsetAsync(counts, 0, (size_t)NN * 4, stream);
    qkv_proj<<<NN / 16, 256, 0, stream>>>(x, Wq, bq, Wk, bk, Wv, bv, Q, K, V);
    hist_k<<<EB, 256, 0, stream>>>(edst, counts);
    scan_a<<<NB, 256, 0, stream>>>(counts, blocksum);
    scan_b<<<1, 256, 0, stream>>>(blocksum, blockoffs, offs);
    scan_c<<<NB, 256, 0, stream>>>(counts, blockoffs, offs, cursor);
    scatter_k<<<EB, 256, 0, stream>>>(esrc, edst, eattr, cursor, sorted);
    gather_reduce<<<NN / 4, 256, 0, stream>>>(Q, K, V, Et, Eft, offs, sorted, (float*)d_out);
}

// Round 5
// 201.603 us; speedup vs baseline: 12.4101x; 1.5103x over previous
//
#include <hip/hip_runtime.h>
#include <hip/hip_bf16.h>
#include <hip/hip_fp16.h>

#define NN      50000
#define INDIM   128
#define HDIM    128      // HEADS*HEAD_DIM
#define EREAL   600000
#define ETOT    650000

typedef unsigned short u16;
typedef _Float16 f16;
typedef _Float16 f16x8 __attribute__((ext_vector_type(8)));
typedef float f32x4 __attribute__((ext_vector_type(4)));

__device__ __forceinline__ float h2f(unsigned int h) {
    __half v; u16 s = (u16)h; __builtin_memcpy(&v, &s, 2); return __half2float(v);
}
__device__ __forceinline__ u16 f2h(float f) {
    __half v = __float2half(f);
    u16 u; __builtin_memcpy(&u, &v, 2); return u;
}

// ---------------------------------------------------------------------------
// One-time: Wt[c][k] = W{q,k,v}[k][c&127] in f16  (c = 0..383, k = 0..127)
// ---------------------------------------------------------------------------
__global__ __launch_bounds__(256) void cvt_w(
    const float* __restrict__ Wq, const float* __restrict__ Wk,
    const float* __restrict__ Wv, f16* __restrict__ Wt)
{
    int t = blockIdx.x * 256 + threadIdx.x;
    if (t >= 384 * 128) return;
    int c = t >> 7, k = t & 127;
    const float* W = (c < 128) ? Wq : (c < 256) ? Wk : Wv;
    Wt[t] = (f16)W[k * 128 + (c & 127)];
}

// ---------------------------------------------------------------------------
// Stage 1: Q/K/V projection via MFMA. Block = 256 thr = 4 waves = 64 nodes.
// Wave w: rows m0..m0+15; iterates 24 col-tiles (8 each for Q,K,V).
// A from global x (f32 -> f16 in reg), B from Wt (f16, L2-resident).
// A/B slot->k map: k = ks*32 + 8*(lane>>4) + e  (same formula both operands).
// C map (m89-verified): col = lane&15, row = 4*(lane>>4) + reg.
// ---------------------------------------------------------------------------
__global__ __launch_bounds__(256) void qkv_mfma(
    const float* __restrict__ x, const f16* __restrict__ Wt,
    const float* __restrict__ bq, const float* __restrict__ bk,
    const float* __restrict__ bv,
    u16* __restrict__ Q, u16* __restrict__ K, u16* __restrict__ V)
{
    const int wave = threadIdx.x >> 6;
    const int lane = threadIdx.x & 63;
    const int g = lane >> 4, ln = lane & 15;
    const int m0 = blockIdx.x * 64 + wave * 16;

    f16x8 A[4];
    {
        int m = m0 + ln; if (m >= NN) m = NN - 1;
        const float* xr = x + (size_t)m * INDIM;
        #pragma unroll
        for (int ks = 0; ks < 4; ks++) {
            const float* p = xr + ks * 32 + g * 8;
            f16x8 a;
            #pragma unroll
            for (int e = 0; e < 8; e++) a[e] = (f16)p[e];
            A[ks] = a;
        }
    }

    #pragma unroll
    for (int ct = 0; ct < 24; ct++) {
        const f16* wp = Wt + ((size_t)(ct * 16 + ln) * 128) + g * 8;
        f32x4 acc = {0.f, 0.f, 0.f, 0.f};
        #pragma unroll
        for (int ks = 0; ks < 4; ks++) {
            f16x8 b = *reinterpret_cast<const f16x8*>(wp + ks * 32);
            acc = __builtin_amdgcn_mfma_f32_16x16x32_f16(A[ks], b, acc, 0, 0, 0);
        }
        const int mt = ct >> 3;                 // 0=Q 1=K 2=V
        const int cc = (ct & 7) * 16 + ln;      // column within matrix
        const float* bp = (mt == 0) ? bq : (mt == 1) ? bk : bv;
        u16* op = (mt == 0) ? Q : (mt == 1) ? K : V;
        const float bias = bp[cc];
        #pragma unroll
        for (int r = 0; r < 4; r++) {
            int nd = m0 + g * 4 + r;
            if (nd < NN) op[(size_t)nd * HDIM + cc] = f2h(acc[r] + bias);
        }
    }
}

// ---------------------------------------------------------------------------
// CSR build: histogram -> hierarchical exclusive scan -> scatter (verified)
// ---------------------------------------------------------------------------
__global__ __launch_bounds__(256) void hist_k(
    const int* __restrict__ edst, int* __restrict__ counts)
{
    int t = blockIdx.x * 256 + threadIdx.x;
    if (t < ETOT) atomicAdd(&counts[edst[t]], 1);
}

__global__ __launch_bounds__(256) void scan_a(
    const int* __restrict__ counts, int* __restrict__ blocksum)
{
    __shared__ int s[256];
    int t = threadIdx.x, b = blockIdx.x;
    int i = b * 256 + t;
    int v = (i < NN) ? counts[i] : 0;
    s[t] = v; __syncthreads();
    for (int d = 128; d > 0; d >>= 1) {
        if (t < d) s[t] += s[t + d];
        __syncthreads();
    }
    if (t == 0) blocksum[b] = s[0];
}

__global__ __launch_bounds__(256) void scan_b(
    const int* __restrict__ blocksum, int* __restrict__ blockoffs,
    int* __restrict__ offs)
{
    __shared__ int s[256];
    int t = threadIdx.x;
    int nb = (NN + 255) / 256;                 // 196
    int v = (t < nb) ? blocksum[t] : 0;
    s[t] = v; __syncthreads();
    for (int d = 1; d < 256; d <<= 1) {
        int add = (t >= d) ? s[t - d] : 0;
        __syncthreads();
        s[t] += add;
        __syncthreads();
    }
    if (t < nb) blockoffs[t] = s[t] - v;       // exclusive
    if (t == 0) offs[NN] = ETOT;
}

__global__ __launch_bounds__(256) void scan_c(
    const int* __restrict__ counts, const int* __restrict__ blockoffs,
    int* __restrict__ offs, int* __restrict__ cursor)
{
    __shared__ int s[256];
    int t = threadIdx.x, b = blockIdx.x;
    int i = b * 256 + t;
    int v = (i < NN) ? counts[i] : 0;
    s[t] = v; __syncthreads();
    for (int d = 1; d < 256; d <<= 1) {
        int add = (t >= d) ? s[t - d] : 0;
        __syncthreads();
        s[t] += add;
        __syncthreads();
    }
    if (i < NN) {
        int off = blockoffs[b] + s[t] - v;     // exclusive
        offs[i] = off;
        cursor[i] = off;
    }
}

__global__ __launch_bounds__(256) void scatter_k(
    const int* __restrict__ esrc, const int* __restrict__ edst,
    const int* __restrict__ eattr,
    int* __restrict__ cursor, int* __restrict__ sorted)
{
    int t = blockIdx.x * 256 + threadIdx.x;
    if (t >= ETOT) return;
    int dest = edst[t];
    int attr = (t < EREAL) ? eattr[t] : 16;    // 16 = fake-edge row
    int pos = atomicAdd(&cursor[dest], 1);
    sorted[pos] = esrc[t] | (attr << 20);
}

// ---------------------------------------------------------------------------
// Stage 2: gather-reduce. One wave per dest node; lane covers 2 elems.
// ---------------------------------------------------------------------------
__global__ __launch_bounds__(256) void gather_reduce(
    const u16* __restrict__ Q, const u16* __restrict__ K, const u16* __restrict__ V,
    const float* __restrict__ Et, const float* __restrict__ Eft,
    const int* __restrict__ offs, const int* __restrict__ sorted,
    float* __restrict__ out)
{
    const int lane = threadIdx.x & 63;
    int n = blockIdx.x * 4 + (threadIdx.x >> 6);
    n = __builtin_amdgcn_readfirstlane(n);     // force SGPR -> s_load path

    const unsigned int* Qp = reinterpret_cast<const unsigned int*>(Q);
    const unsigned int* Kp = reinterpret_cast<const unsigned int*>(K);
    const unsigned int* Vp = reinterpret_cast<const unsigned int*>(V);

    unsigned int qu = Qp[(size_t)n * 64 + lane];
    const float q0 = h2f(qu & 0xffffu), q1 = h2f(qu >> 16);

    float accx = 0.f, accy = 0.f, zacc = 0.f;
    const int base = offs[n], end = offs[n + 1];

    for (int i = base; i < end; ++i) {
        int rec  = sorted[i];
        int src  = rec & 0xFFFFF;
        int attr = rec >> 20;
        unsigned int ku = Kp[(size_t)src * 64 + lane];
        unsigned int vu = Vp[(size_t)src * 64 + lane];
        const float* ep = (attr < 16) ? (Et + attr * HDIM) : Eft;
        float2 e = *reinterpret_cast<const float2*>(ep + 2 * lane);

        float p = h2f(ku & 0xffffu) * q0 * e.x + h2f(ku >> 16) * q1 * e.y;
        p += __shfl_xor(p, 1);
        p += __shfl_xor(p, 2);
        p += __shfl_xor(p, 4);
        float s  = fminf(fmaxf(p * 0.25f, -5.f), 5.f);
        float sc = __expf(s);

        accx += h2f(vu & 0xffffu) * sc;
        accy += h2f(vu >> 16) * sc;
        zacc += sc;
    }

    float inv = 1.f / (zacc + 1e-6f);
    float2 o; o.x = accx * inv; o.y = accy * inv;
    *reinterpret_cast<float2*>(out + (size_t)n * HDIM + 2 * lane) = o;
}

extern "C" void kernel_launch(void* const* d_in, const int* in_sizes, int n_in,
                              void* d_out, int out_size, void* d_ws, size_t ws_size,
                              hipStream_t stream)
{
    const float* x   = (const float*)d_in[0];
    const float* Wq  = (const float*)d_in[1];
    const float* bq  = (const float*)d_in[2];
    const float* Wk  = (const float*)d_in[3];
    const float* bk  = (const float*)d_in[4];
    const float* Wv  = (const float*)d_in[5];
    const float* bv  = (const float*)d_in[6];
    const float* Et  = (const float*)d_in[7];
    const float* Eft = (const float*)d_in[8];
    const int* eattr = (const int*)d_in[9];
    const int* esrc  = (const int*)d_in[11];
    const int* edst  = (const int*)d_in[12];

    char* ws = (char*)d_ws;
    const size_t qkv_bytes = (size_t)NN * HDIM * sizeof(u16);       // 12,800,000
    u16* Q = (u16*)(ws);
    u16* K = (u16*)(ws + qkv_bytes);
    u16* V = (u16*)(ws + 2 * qkv_bytes);
    size_t off = 3 * qkv_bytes;                                     // 38,400,000
    int* offs      = (int*)(ws + off); off += ((NN + 1) * 4 + 12) & ~15ull;
    int* cursor    = (int*)(ws + off); off += (size_t)NN * 4;
    int* counts    = (int*)(ws + off); off += (size_t)NN * 4;
    int* blocksum  = (int*)(ws + off); off += 1024;
    int* blockoffs = (int*)(ws + off); off += 1024;
    int* sorted    = (int*)(ws + off); off += (size_t)ETOT * 4;     // 2.6 MB
    f16* Wt        = (f16*)(ws + off);                              // 96 KB

    const int NB = (NN + 255) / 256;       // 196
    const int EB = (ETOT + 255) / 256;     // 2540

    hipMemsetAsync(counts, 0, (size_t)NN * 4, stream);
    cvt_w<<<192, 256, 0, stream>>>(Wq, Wk, Wv, Wt);
    qkv_mfma<<<(NN + 63) / 64, 256, 0, stream>>>(x, Wt, bq, bk, bv, Q, K, V);
    hist_k<<<EB, 256, 0, stream>>>(edst, counts);
    scan_a<<<NB, 256, 0, stream>>>(counts, blocksum);
    scan_b<<<1, 256, 0, stream>>>(blocksum, blockoffs, offs);
    scan_c<<<NB, 256, 0, stream>>>(counts, blockoffs, offs, cursor);
    scatter_k<<<EB, 256, 0, stream>>>(esrc, edst, eattr, cursor, sorted);
    gather_reduce<<<NN / 4, 256, 0, stream>>>(Q, K, V, Et, Eft, offs, sorted, (float*)d_out);
}

// Round 6
// 188.169 us; speedup vs baseline: 13.2961x; 1.0714x over previous
//
#include <hip/hip_runtime.h>
#include <hip/hip_bf16.h>
#include <hip/hip_fp16.h>

#define NN      50000
#define INDIM   128
#define HDIM    128      // HEADS*HEAD_DIM
#define EREAL   600000
#define ETOT    650000

typedef unsigned short u16;
typedef _Float16 f16;
typedef _Float16 f16x8 __attribute__((ext_vector_type(8)));
typedef float f32x4 __attribute__((ext_vector_type(4)));

__device__ __forceinline__ float h2f(unsigned int h) {
    __half v; u16 s = (u16)h; __builtin_memcpy(&v, &s, 2); return __half2float(v);
}
__device__ __forceinline__ u16 f2h(float f) {
    __half v = __float2half(f);
    u16 u; __builtin_memcpy(&u, &v, 2); return u;
}

// ---------------------------------------------------------------------------
// One-time: Wt[c][k] = W{q,k,v}[k][c&127] in f16  (c = 0..383, k = 0..127)
// ---------------------------------------------------------------------------
__global__ __launch_bounds__(256) void cvt_w(
    const float* __restrict__ Wq, const float* __restrict__ Wk,
    const float* __restrict__ Wv, f16* __restrict__ Wt)
{
    int t = blockIdx.x * 256 + threadIdx.x;
    if (t >= 384 * 128) return;
    int c = t >> 7, k = t & 127;
    const float* W = (c < 128) ? Wq : (c < 256) ? Wk : Wv;
    Wt[t] = (f16)W[k * 128 + (c & 127)];
}

// ---------------------------------------------------------------------------
// Stage 1: Q/K/V projection via MFMA. Block = 256 thr = 4 waves = 64 nodes.
// A from global x (float4 loads, f32->f16 in reg), B from Wt (L2-resident).
// Results staged in LDS (row stride 136 u16 -> 68 dwords = 4 mod 32, no
// meaningful bank conflicts), then stored coalesced as uint4.
// ---------------------------------------------------------------------------
__global__ __launch_bounds__(256) void qkv_mfma(
    const float* __restrict__ x, const f16* __restrict__ Wt,
    const float* __restrict__ bq, const float* __restrict__ bk,
    const float* __restrict__ bv,
    u16* __restrict__ Q, u16* __restrict__ K, u16* __restrict__ V)
{
    __shared__ u16 st[3][64][136];             // 52,224 B
    const int wave = threadIdx.x >> 6;
    const int lane = threadIdx.x & 63;
    const int g = lane >> 4, ln = lane & 15;
    const int m0 = blockIdx.x * 64 + wave * 16;

    f16x8 A[4];
    {
        int m = m0 + ln; if (m >= NN) m = NN - 1;
        const float4* xr = reinterpret_cast<const float4*>(x + (size_t)m * INDIM);
        #pragma unroll
        for (int ks = 0; ks < 4; ks++) {
            float4 u0 = xr[ks * 8 + g * 2];
            float4 u1 = xr[ks * 8 + g * 2 + 1];
            f16x8 a;
            a[0]=(f16)u0.x; a[1]=(f16)u0.y; a[2]=(f16)u0.z; a[3]=(f16)u0.w;
            a[4]=(f16)u1.x; a[5]=(f16)u1.y; a[6]=(f16)u1.z; a[7]=(f16)u1.w;
            A[ks] = a;
        }
    }

    #pragma unroll
    for (int ct = 0; ct < 24; ct++) {
        const f16* wp = Wt + ((size_t)(ct * 16 + ln) * 128) + g * 8;
        f32x4 acc = {0.f, 0.f, 0.f, 0.f};
        #pragma unroll
        for (int ks = 0; ks < 4; ks++) {
            f16x8 b = *reinterpret_cast<const f16x8*>(wp + ks * 32);
            acc = __builtin_amdgcn_mfma_f32_16x16x32_f16(A[ks], b, acc, 0, 0, 0);
        }
        const int mt = ct >> 3;                 // 0=Q 1=K 2=V
        const int cc = (ct & 7) * 16 + ln;      // column within matrix
        const float* bp = (mt == 0) ? bq : (mt == 1) ? bk : bv;
        const float bias = bp[cc];
        #pragma unroll
        for (int r = 0; r < 4; r++)
            st[mt][wave * 16 + g * 4 + r][cc] = f2h(acc[r] + bias);
    }
    __syncthreads();

    // coalesced writeback: 3 matrices x 64 rows x 16 uint4-chunks = 3072
    #pragma unroll
    for (int j = 0; j < 12; j++) {
        int c = threadIdx.x + 256 * j;          // 0..3071
        int mtx  = c >> 10;
        int row  = (c >> 4) & 63;
        int col8 = c & 15;                       // ushort8 chunk within row
        int nd = blockIdx.x * 64 + row;
        if (nd < NN) {
            u16* op = (mtx == 0) ? Q : (mtx == 1) ? K : V;
            uint4 v = *reinterpret_cast<const uint4*>(&st[mtx][row][col8 * 8]);
            *reinterpret_cast<uint4*>(op + (size_t)nd * HDIM + col8 * 8) = v;
        }
    }
}

// ---------------------------------------------------------------------------
// CSR build: histogram -> scan (2 kernels) -> scatter
// ---------------------------------------------------------------------------
__global__ __launch_bounds__(256) void hist_k(
    const int* __restrict__ edst, int* __restrict__ counts)
{
    int t = blockIdx.x * 256 + threadIdx.x;
    if (t < ETOT) atomicAdd(&counts[edst[t]], 1);
}

__global__ __launch_bounds__(256) void scan_a(
    const int* __restrict__ counts, int* __restrict__ blocksum)
{
    __shared__ int s[256];
    int t = threadIdx.x, b = blockIdx.x;
    int i = b * 256 + t;
    int v = (i < NN) ? counts[i] : 0;
    s[t] = v; __syncthreads();
    for (int d = 128; d > 0; d >>= 1) {
        if (t < d) s[t] += s[t + d];
        __syncthreads();
    }
    if (t == 0) blocksum[b] = s[0];
}

// fused scan_b + scan_c: every block scans the 196 block sums redundantly,
// then does its local 256-elem exclusive scan.
__global__ __launch_bounds__(256) void scan_bc(
    const int* __restrict__ counts, const int* __restrict__ blocksum,
    int* __restrict__ offs, int* __restrict__ cursor)
{
    __shared__ int bs[256];
    __shared__ int s[256];
    int t = threadIdx.x, b = blockIdx.x;
    const int nb = (NN + 255) / 256;           // 196
    int bv = (t < nb) ? blocksum[t] : 0;
    bs[t] = bv; __syncthreads();
    // inclusive scan of bs in s
    s[t] = bs[t]; __syncthreads();
    for (int d = 1; d < 256; d <<= 1) {
        int add = (t >= d) ? s[t - d] : 0;
        __syncthreads();
        s[t] += add;
        __syncthreads();
    }
    const int blockoff = s[b] - bs[b];         // exclusive sum up to block b
    __syncthreads();

    int i = b * 256 + t;
    int v = (i < NN) ? counts[i] : 0;
    s[t] = v; __syncthreads();
    for (int d = 1; d < 256; d <<= 1) {
        int add = (t >= d) ? s[t - d] : 0;
        __syncthreads();
        s[t] += add;
        __syncthreads();
    }
    if (i < NN) {
        int off = blockoff + s[t] - v;         // exclusive
        offs[i] = off;
        cursor[i] = off;
    }
    if (b == 0 && t == 0) offs[NN] = ETOT;
}

__global__ __launch_bounds__(256) void scatter_k(
    const int* __restrict__ esrc, const int* __restrict__ edst,
    const int* __restrict__ eattr,
    int* __restrict__ cursor, int* __restrict__ sorted)
{
    int t = blockIdx.x * 256 + threadIdx.x;
    if (t >= ETOT) return;
    int dest = edst[t];
    int attr = (t < EREAL) ? eattr[t] : 16;    // 16 = fake-edge row
    int pos = atomicAdd(&cursor[dest], 1);
    sorted[pos] = esrc[t] | (attr << 20);
}

// ---------------------------------------------------------------------------
// Stage 2: gather-reduce, unroll-by-2 for 2x memory-level parallelism.
// One wave per dest node; lane covers 2 elems; recs via s_load (uniform idx).
// ---------------------------------------------------------------------------
__global__ __launch_bounds__(256) void gather_reduce(
    const u16* __restrict__ Q, const u16* __restrict__ K, const u16* __restrict__ V,
    const float* __restrict__ Et, const float* __restrict__ Eft,
    const int* __restrict__ offs, const int* __restrict__ sorted,
    float* __restrict__ out)
{
    const int lane = threadIdx.x & 63;
    int n = blockIdx.x * 4 + (threadIdx.x >> 6);
    n = __builtin_amdgcn_readfirstlane(n);     // SGPR -> s_load path

    const unsigned int* Qp = reinterpret_cast<const unsigned int*>(Q);
    const unsigned int* Kp = reinterpret_cast<const unsigned int*>(K);
    const unsigned int* Vp = reinterpret_cast<const unsigned int*>(V);

    unsigned int qu = Qp[(size_t)n * 64 + lane];
    const float q0 = h2f(qu & 0xffffu), q1 = h2f(qu >> 16);

    float accx = 0.f, accy = 0.f, zacc = 0.f;
    int i = offs[n];
    const int end = offs[n + 1];

    for (; i + 1 < end; i += 2) {
        int recA = sorted[i];
        int recB = sorted[i + 1];
        int srcA = recA & 0xFFFFF, attrA = recA >> 20;
        int srcB = recB & 0xFFFFF, attrB = recB >> 20;
        unsigned int kuA = Kp[(size_t)srcA * 64 + lane];
        unsigned int vuA = Vp[(size_t)srcA * 64 + lane];
        unsigned int kuB = Kp[(size_t)srcB * 64 + lane];
        unsigned int vuB = Vp[(size_t)srcB * 64 + lane];
        const float* epA = (attrA < 16) ? (Et + attrA * HDIM) : Eft;
        const float* epB = (attrB < 16) ? (Et + attrB * HDIM) : Eft;
        float2 eA = *reinterpret_cast<const float2*>(epA + 2 * lane);
        float2 eB = *reinterpret_cast<const float2*>(epB + 2 * lane);

        float pA = h2f(kuA & 0xffffu) * q0 * eA.x + h2f(kuA >> 16) * q1 * eA.y;
        float pB = h2f(kuB & 0xffffu) * q0 * eB.x + h2f(kuB >> 16) * q1 * eB.y;
        pA += __shfl_xor(pA, 1);  pB += __shfl_xor(pB, 1);
        pA += __shfl_xor(pA, 2);  pB += __shfl_xor(pB, 2);
        pA += __shfl_xor(pA, 4);  pB += __shfl_xor(pB, 4);
        float scA = __expf(fminf(fmaxf(pA * 0.25f, -5.f), 5.f));
        float scB = __expf(fminf(fmaxf(pB * 0.25f, -5.f), 5.f));

        accx += h2f(vuA & 0xffffu) * scA;  accy += h2f(vuA >> 16) * scA;  zacc += scA;
        accx += h2f(vuB & 0xffffu) * scB;  accy += h2f(vuB >> 16) * scB;  zacc += scB;
    }
    if (i < end) {
        int rec  = sorted[i];
        int src  = rec & 0xFFFFF, attr = rec >> 20;
        unsigned int ku = Kp[(size_t)src * 64 + lane];
        unsigned int vu = Vp[(size_t)src * 64 + lane];
        const float* ep = (attr < 16) ? (Et + attr * HDIM) : Eft;
        float2 e = *reinterpret_cast<const float2*>(ep + 2 * lane);
        float p = h2f(ku & 0xffffu) * q0 * e.x + h2f(ku >> 16) * q1 * e.y;
        p += __shfl_xor(p, 1);
        p += __shfl_xor(p, 2);
        p += __shfl_xor(p, 4);
        float sc = __expf(fminf(fmaxf(p * 0.25f, -5.f), 5.f));
        accx += h2f(vu & 0xffffu) * sc;  accy += h2f(vu >> 16) * sc;  zacc += sc;
    }

    float inv = 1.f / (zacc + 1e-6f);
    float2 o; o.x = accx * inv; o.y = accy * inv;
    *reinterpret_cast<float2*>(out + (size_t)n * HDIM + 2 * lane) = o;
}

extern "C" void kernel_launch(void* const* d_in, const int* in_sizes, int n_in,
                              void* d_out, int out_size, void* d_ws, size_t ws_size,
                              hipStream_t stream)
{
    const float* x   = (const float*)d_in[0];
    const float* Wq  = (const float*)d_in[1];
    const float* bq  = (const float*)d_in[2];
    const float* Wk  = (const float*)d_in[3];
    const float* bk  = (const float*)d_in[4];
    const float* Wv  = (const float*)d_in[5];
    const float* bv  = (const float*)d_in[6];
    const float* Et  = (const float*)d_in[7];
    const float* Eft = (const float*)d_in[8];
    const int* eattr = (const int*)d_in[9];
    const int* esrc  = (const int*)d_in[11];
    const int* edst  = (const int*)d_in[12];

    char* ws = (char*)d_ws;
    const size_t qkv_bytes = (size_t)NN * HDIM * sizeof(u16);       // 12,800,000
    u16* Q = (u16*)(ws);
    u16* K = (u16*)(ws + qkv_bytes);
    u16* V = (u16*)(ws + 2 * qkv_bytes);
    size_t off = 3 * qkv_bytes;                                     // 38,400,000
    int* offs      = (int*)(ws + off); off += ((NN + 1) * 4 + 12) & ~15ull;
    int* cursor    = (int*)(ws + off); off += (size_t)NN * 4;
    int* counts    = (int*)(ws + off); off += (size_t)NN * 4;
    int* blocksum  = (int*)(ws + off); off += 1024;
    int* sorted    = (int*)(ws + off); off += (size_t)ETOT * 4;     // 2.6 MB
    f16* Wt        = (f16*)(ws + off);                              // 96 KB

    const int NB = (NN + 255) / 256;       // 196
    const int EB = (ETOT + 255) / 256;     // 2540

    hipMemsetAsync(counts, 0, (size_t)NN * 4, stream);
    cvt_w<<<192, 256, 0, stream>>>(Wq, Wk, Wv, Wt);
    qkv_mfma<<<(NN + 63) / 64, 256, 0, stream>>>(x, Wt, bq, bk, bv, Q, K, V);
    hist_k<<<EB, 256, 0, stream>>>(edst, counts);
    scan_a<<<NB, 256, 0, stream>>>(counts, blocksum);
    scan_bc<<<NB, 256, 0, stream>>>(counts, blocksum, offs, cursor);
    scatter_k<<<EB, 256, 0, stream>>>(esrc, edst, eattr, cursor, sorted);
    gather_reduce<<<NN / 4, 256, 0, stream>>>(Q, K, V, Et, Eft, offs, sorted, (float*)d_out);
}

// Round 7
// 176.560 us; speedup vs baseline: 14.1704x; 1.0658x over previous
//
#include <hip/hip_runtime.h>
#include <hip/hip_bf16.h>
#include <hip/hip_fp16.h>

#define NN      50000
#define INDIM   128
#define HDIM    128      // HEADS*HEAD_DIM
#define EREAL   600000
#define ETOT    650000

#define QKVB    782      // ceil(NN/64) qkv blocks
#define HISTB   2540     // ceil(ETOT/256)
#define CVTB    192      // 384*128/256
#define ZEROB   196      // ceil(NN/256)

typedef unsigned short u16;
typedef _Float16 f16;
typedef _Float16 f16x8 __attribute__((ext_vector_type(8)));
typedef float f32x4 __attribute__((ext_vector_type(4)));

__device__ __forceinline__ float h2f(unsigned int h) {
    __half v; u16 s = (u16)h; __builtin_memcpy(&v, &s, 2); return __half2float(v);
}
__device__ __forceinline__ u16 f2h(float f) {
    __half v = __float2half(f);
    u16 u; __builtin_memcpy(&u, &v, 2); return u;
}

// ---------------------------------------------------------------------------
// fused_init: blocks [0,CVTB) build Wt[c][k] f16; blocks [CVTB, CVTB+ZEROB)
// zero the counts array. Independent work, one dispatch.
// ---------------------------------------------------------------------------
__global__ __launch_bounds__(256) void fused_init(
    const float* __restrict__ Wq, const float* __restrict__ Wk,
    const float* __restrict__ Wv, f16* __restrict__ Wt,
    int* __restrict__ counts)
{
    if (blockIdx.x < CVTB) {
        int t = blockIdx.x * 256 + threadIdx.x;          // < 49152 always
        int c = t >> 7, k = t & 127;
        const float* W = (c < 128) ? Wq : (c < 256) ? Wk : Wv;
        Wt[t] = (f16)W[k * 128 + (c & 127)];
    } else {
        int i = (blockIdx.x - CVTB) * 256 + threadIdx.x;
        if (i < NN) counts[i] = 0;
    }
}

// ---------------------------------------------------------------------------
// fused_qkv_hist: blocks [0,QKVB) do the MFMA projection; blocks
// [QKVB, QKVB+HISTB) do the dest histogram. Independent work.
//
// QKV: swapped operands — D = Wtile * xtile, so D row = channel (4g+r),
// D col = node (lane&15). Each lane stores ushort4 (4 consecutive channels
// of one node). No LDS.
// ---------------------------------------------------------------------------
__global__ __launch_bounds__(256) void fused_qkv_hist(
    const float* __restrict__ x, const f16* __restrict__ Wt,
    const float* __restrict__ bq, const float* __restrict__ bk,
    const float* __restrict__ bv,
    u16* __restrict__ Q, u16* __restrict__ K, u16* __restrict__ V,
    const int* __restrict__ edst, int* __restrict__ counts)
{
    if (blockIdx.x >= QKVB) {
        int t = (blockIdx.x - QKVB) * 256 + threadIdx.x;
        if (t < ETOT) atomicAdd(&counts[edst[t]], 1);
        return;
    }

    const int wave = threadIdx.x >> 6;
    const int lane = threadIdx.x & 63;
    const int g = lane >> 4, ln = lane & 15;
    const int m0 = blockIdx.x * 64 + wave * 16;          // wave's node base
    const int node = m0 + ln;

    // B operand: x row (node ln), k = ks*32 + 8g + e, f32 -> f16
    f16x8 Bx[4];
    {
        int m = node < NN ? node : NN - 1;
        const float4* xr = reinterpret_cast<const float4*>(x + (size_t)m * INDIM);
        #pragma unroll
        for (int ks = 0; ks < 4; ks++) {
            float4 u0 = xr[ks * 8 + g * 2];
            float4 u1 = xr[ks * 8 + g * 2 + 1];
            f16x8 a;
            a[0]=(f16)u0.x; a[1]=(f16)u0.y; a[2]=(f16)u0.z; a[3]=(f16)u0.w;
            a[4]=(f16)u1.x; a[5]=(f16)u1.y; a[6]=(f16)u1.z; a[7]=(f16)u1.w;
            Bx[ks] = a;
        }
    }
    const bool live = (node < NN);

    #pragma unroll
    for (int ct = 0; ct < 24; ct++) {
        // A operand: Wt row (channel ct*16+ln), same k mapping
        const f16* wp = Wt + ((size_t)(ct * 16 + ln) * 128) + g * 8;
        f32x4 acc = {0.f, 0.f, 0.f, 0.f};
        #pragma unroll
        for (int ks = 0; ks < 4; ks++) {
            f16x8 aw = *reinterpret_cast<const f16x8*>(wp + ks * 32);
            acc = __builtin_amdgcn_mfma_f32_16x16x32_f16(aw, Bx[ks], acc, 0, 0, 0);
        }
        const int mt  = ct >> 3;                 // 0=Q 1=K 2=V
        const int ch0 = (ct & 7) * 16 + g * 4;   // this lane's 4 channels
        const float* bp = (mt == 0) ? bq : (mt == 1) ? bk : bv;
        u16* op = (mt == 0) ? Q : (mt == 1) ? K : V;
        float4 bias = *reinterpret_cast<const float4*>(bp + ch0);
        if (live) {
            ushort4 o;
            o.x = f2h(acc[0] + bias.x); o.y = f2h(acc[1] + bias.y);
            o.z = f2h(acc[2] + bias.z); o.w = f2h(acc[3] + bias.w);
            *reinterpret_cast<ushort4*>(op + (size_t)node * HDIM + ch0) = o;
        }
    }
}

// ---------------------------------------------------------------------------
// CSR scan: per-block sums, then fused global scan + local scan
// ---------------------------------------------------------------------------
__global__ __launch_bounds__(256) void scan_a(
    const int* __restrict__ counts, int* __restrict__ blocksum)
{
    __shared__ int s[256];
    int t = threadIdx.x, b = blockIdx.x;
    int i = b * 256 + t;
    int v = (i < NN) ? counts[i] : 0;
    s[t] = v; __syncthreads();
    for (int d = 128; d > 0; d >>= 1) {
        if (t < d) s[t] += s[t + d];
        __syncthreads();
    }
    if (t == 0) blocksum[b] = s[0];
}

__global__ __launch_bounds__(256) void scan_bc(
    const int* __restrict__ counts, const int* __restrict__ blocksum,
    int* __restrict__ offs, int* __restrict__ cursor)
{
    __shared__ int bs[256];
    __shared__ int s[256];
    int t = threadIdx.x, b = blockIdx.x;
    const int nb = ZEROB;                      // 196
    int bv = (t < nb) ? blocksum[t] : 0;
    bs[t] = bv; __syncthreads();
    s[t] = bs[t]; __syncthreads();
    for (int d = 1; d < 256; d <<= 1) {
        int add = (t >= d) ? s[t - d] : 0;
        __syncthreads();
        s[t] += add;
        __syncthreads();
    }
    const int blockoff = s[b] - bs[b];
    __syncthreads();

    int i = b * 256 + t;
    int v = (i < NN) ? counts[i] : 0;
    s[t] = v; __syncthreads();
    for (int d = 1; d < 256; d <<= 1) {
        int add = (t >= d) ? s[t - d] : 0;
        __syncthreads();
        s[t] += add;
        __syncthreads();
    }
    if (i < NN) {
        int off = blockoff + s[t] - v;
        offs[i] = off;
        cursor[i] = off;
    }
    if (b == 0 && t == 0) offs[NN] = ETOT;
}

__global__ __launch_bounds__(256) void scatter_k(
    const int* __restrict__ esrc, const int* __restrict__ edst,
    const int* __restrict__ eattr,
    int* __restrict__ cursor, int* __restrict__ sorted)
{
    int t = blockIdx.x * 256 + threadIdx.x;
    if (t >= ETOT) return;
    int dest = edst[t];
    int attr = (t < EREAL) ? eattr[t] : 16;    // 16 = fake-edge row
    int pos = atomicAdd(&cursor[dest], 1);
    sorted[pos] = esrc[t] | (attr << 20);
}

// ---------------------------------------------------------------------------
// gather-reduce, unroll-by-4. One wave per dest node; lane covers 2 elems.
// ---------------------------------------------------------------------------
__global__ __launch_bounds__(256) void gather_reduce(
    const u16* __restrict__ Q, const u16* __restrict__ K, const u16* __restrict__ V,
    const float* __restrict__ Et, const float* __restrict__ Eft,
    const int* __restrict__ offs, const int* __restrict__ sorted,
    float* __restrict__ out)
{
    const int lane = threadIdx.x & 63;
    int n = blockIdx.x * 4 + (threadIdx.x >> 6);
    n = __builtin_amdgcn_readfirstlane(n);

    const unsigned int* Qp = reinterpret_cast<const unsigned int*>(Q);
    const unsigned int* Kp = reinterpret_cast<const unsigned int*>(K);
    const unsigned int* Vp = reinterpret_cast<const unsigned int*>(V);

    unsigned int qu = Qp[(size_t)n * 64 + lane];
    const float q0 = h2f(qu & 0xffffu) * 0.25f, q1 = h2f(qu >> 16) * 0.25f;

    float accx = 0.f, accy = 0.f, zacc = 0.f;
    int i = offs[n];
    const int end = offs[n + 1];

    for (; i + 3 < end; i += 4) {
        int rec0 = sorted[i],     rec1 = sorted[i + 1];
        int rec2 = sorted[i + 2], rec3 = sorted[i + 3];
        int s0 = rec0 & 0xFFFFF, s1 = rec1 & 0xFFFFF;
        int s2 = rec2 & 0xFFFFF, s3 = rec3 & 0xFFFFF;
        unsigned int ku0 = Kp[(size_t)s0 * 64 + lane];
        unsigned int ku1 = Kp[(size_t)s1 * 64 + lane];
        unsigned int ku2 = Kp[(size_t)s2 * 64 + lane];
        unsigned int ku3 = Kp[(size_t)s3 * 64 + lane];
        unsigned int vu0 = Vp[(size_t)s0 * 64 + lane];
        unsigned int vu1 = Vp[(size_t)s1 * 64 + lane];
        unsigned int vu2 = Vp[(size_t)s2 * 64 + lane];
        unsigned int vu3 = Vp[(size_t)s3 * 64 + lane];
        int a0 = rec0 >> 20, a1 = rec1 >> 20, a2 = rec2 >> 20, a3 = rec3 >> 20;
        float2 e0 = *reinterpret_cast<const float2*>(((a0 < 16) ? (Et + a0 * HDIM) : Eft) + 2 * lane);
        float2 e1 = *reinterpret_cast<const float2*>(((a1 < 16) ? (Et + a1 * HDIM) : Eft) + 2 * lane);
        float2 e2 = *reinterpret_cast<const float2*>(((a2 < 16) ? (Et + a2 * HDIM) : Eft) + 2 * lane);
        float2 e3 = *reinterpret_cast<const float2*>(((a3 < 16) ? (Et + a3 * HDIM) : Eft) + 2 * lane);

        float p0 = h2f(ku0 & 0xffffu) * q0 * e0.x + h2f(ku0 >> 16) * q1 * e0.y;
        float p1 = h2f(ku1 & 0xffffu) * q0 * e1.x + h2f(ku1 >> 16) * q1 * e1.y;
        float p2 = h2f(ku2 & 0xffffu) * q0 * e2.x + h2f(ku2 >> 16) * q1 * e2.y;
        float p3 = h2f(ku3 & 0xffffu) * q0 * e3.x + h2f(ku3 >> 16) * q1 * e3.y;
        p0 += __shfl_xor(p0, 1); p1 += __shfl_xor(p1, 1);
        p2 += __shfl_xor(p2, 1); p3 += __shfl_xor(p3, 1);
        p0 += __shfl_xor(p0, 2); p1 += __shfl_xor(p1, 2);
        p2 += __shfl_xor(p2, 2); p3 += __shfl_xor(p3, 2);
        p0 += __shfl_xor(p0, 4); p1 += __shfl_xor(p1, 4);
        p2 += __shfl_xor(p2, 4); p3 += __shfl_xor(p3, 4);
        float c0 = __expf(fminf(fmaxf(p0, -5.f), 5.f));
        float c1 = __expf(fminf(fmaxf(p1, -5.f), 5.f));
        float c2 = __expf(fminf(fmaxf(p2, -5.f), 5.f));
        float c3 = __expf(fminf(fmaxf(p3, -5.f), 5.f));

        accx += h2f(vu0 & 0xffffu) * c0 + h2f(vu1 & 0xffffu) * c1
              + h2f(vu2 & 0xffffu) * c2 + h2f(vu3 & 0xffffu) * c3;
        accy += h2f(vu0 >> 16) * c0 + h2f(vu1 >> 16) * c1
              + h2f(vu2 >> 16) * c2 + h2f(vu3 >> 16) * c3;
        zacc += c0 + c1 + c2 + c3;
    }
    for (; i < end; ++i) {
        int rec  = sorted[i];
        int src  = rec & 0xFFFFF, attr = rec >> 20;
        unsigned int ku = Kp[(size_t)src * 64 + lane];
        unsigned int vu = Vp[(size_t)src * 64 + lane];
        const float* ep = (attr < 16) ? (Et + attr * HDIM) : Eft;
        float2 e = *reinterpret_cast<const float2*>(ep + 2 * lane);
        float p = h2f(ku & 0xffffu) * q0 * e.x + h2f(ku >> 16) * q1 * e.y;
        p += __shfl_xor(p, 1);
        p += __shfl_xor(p, 2);
        p += __shfl_xor(p, 4);
        float sc = __expf(fminf(fmaxf(p, -5.f), 5.f));
        accx += h2f(vu & 0xffffu) * sc;  accy += h2f(vu >> 16) * sc;  zacc += sc;
    }

    float inv = 1.f / (zacc + 1e-6f);
    float2 o; o.x = accx * inv; o.y = accy * inv;
    *reinterpret_cast<float2*>(out + (size_t)n * HDIM + 2 * lane) = o;
}

extern "C" void kernel_launch(void* const* d_in, const int* in_sizes, int n_in,
                              void* d_out, int out_size, void* d_ws, size_t ws_size,
                              hipStream_t stream)
{
    const float* x   = (const float*)d_in[0];
    const float* Wq  = (const float*)d_in[1];
    const float* bq  = (const float*)d_in[2];
    const float* Wk  = (const float*)d_in[3];
    const float* bk  = (const float*)d_in[4];
    const float* Wv  = (const float*)d_in[5];
    const float* bv  = (const float*)d_in[6];
    const float* Et  = (const float*)d_in[7];
    const float* Eft = (const float*)d_in[8];
    const int* eattr = (const int*)d_in[9];
    const int* esrc  = (const int*)d_in[11];
    const int* edst  = (const int*)d_in[12];

    char* ws = (char*)d_ws;
    const size_t qkv_bytes = (size_t)NN * HDIM * sizeof(u16);       // 12,800,000
    u16* Q = (u16*)(ws);
    u16* K = (u16*)(ws + qkv_bytes);
    u16* V = (u16*)(ws + 2 * qkv_bytes);
    size_t off = 3 * qkv_bytes;
    int* offs      = (int*)(ws + off); off += ((NN + 1) * 4 + 12) & ~15ull;
    int* cursor    = (int*)(ws + off); off += (size_t)NN * 4;
    int* counts    = (int*)(ws + off); off += (size_t)NN * 4;
    int* blocksum  = (int*)(ws + off); off += 1024;
    int* sorted    = (int*)(ws + off); off += (size_t)ETOT * 4;     // 2.6 MB
    f16* Wt        = (f16*)(ws + off);                              // 96 KB

    const int EB = HISTB;       // 2540

    fused_init<<<CVTB + ZEROB, 256, 0, stream>>>(Wq, Wk, Wv, Wt, counts);
    fused_qkv_hist<<<QKVB + HISTB, 256, 0, stream>>>(x, Wt, bq, bk, bv, Q, K, V, edst, counts);
    scan_a<<<ZEROB, 256, 0, stream>>>(counts, blocksum);
    scan_bc<<<ZEROB, 256, 0, stream>>>(counts, blocksum, offs, cursor);
    scatter_k<<<EB, 256, 0, stream>>>(esrc, edst, eattr, cursor, sorted);
    gather_reduce<<<NN / 4, 256, 0, stream>>>(Q, K, V, Et, Eft, offs, sorted, (float*)d_out);
}

// Round 8
// 174.229 us; speedup vs baseline: 14.3600x; 1.0134x over previous
//
#include <hip/hip_runtime.h>
#include <hip/hip_bf16.h>
#include <hip/hip_fp16.h>

#define NN      50000
#define INDIM   128
#define HDIM    128      // HEADS*HEAD_DIM
#define EREAL   600000
#define ETOT    650000
#define TILES   3125     // NN/16 exactly

#define HISTB   2540     // ceil(ETOT/256)
#define CVTB    192      // 384*128/256
#define ZEROB   196      // ceil(NN/256)
#define QKVB    782      // ceil(3128 waves / 4)

typedef unsigned short u16;
typedef _Float16 f16;
typedef _Float16 f16x8 __attribute__((ext_vector_type(8)));
typedef float f32x4 __attribute__((ext_vector_type(4)));

__device__ __forceinline__ float h2f(unsigned int h) {
    __half v; u16 s = (u16)h; __builtin_memcpy(&v, &s, 2); return __half2float(v);
}
__device__ __forceinline__ u16 f2h(float f) {
    __half v = __float2half(f);
    u16 u; __builtin_memcpy(&u, &v, 2); return u;
}
__device__ __forceinline__ f16x8 cvt2(float4 a, float4 b) {
    f16x8 r;
    r[0]=(f16)a.x; r[1]=(f16)a.y; r[2]=(f16)a.z; r[3]=(f16)a.w;
    r[4]=(f16)b.x; r[5]=(f16)b.y; r[6]=(f16)b.z; r[7]=(f16)b.w;
    return r;
}

// ---------------------------------------------------------------------------
// fused_init: blocks [0,CVTB) build Wt[c][k] f16; blocks [CVTB,CVTB+HISTB)
// do the dest histogram (counts pre-zeroed by memset on the stream).
// ---------------------------------------------------------------------------
__global__ __launch_bounds__(256) void fused_init(
    const float* __restrict__ Wq, const float* __restrict__ Wk,
    const float* __restrict__ Wv, f16* __restrict__ Wt,
    const int* __restrict__ edst, int* __restrict__ counts)
{
    if (blockIdx.x < CVTB) {
        int t = blockIdx.x * 256 + threadIdx.x;          // < 49152 always
        int c = t >> 7, k = t & 127;
        const float* W = (c < 128) ? Wq : (c < 256) ? Wk : Wv;
        Wt[t] = (f16)W[k * 128 + (c & 127)];
    } else {
        int t = (blockIdx.x - CVTB) * 256 + threadIdx.x;
        if (t < ETOT) atomicAdd(&counts[edst[t]], 1);
    }
}

// ---------------------------------------------------------------------------
// Stage 1: QKV projection. Wave owns 3 ct-tiles (Wt fragments + bias hoisted,
// held in registers), streams 8 node-tiles with ping-pong x prefetch.
// D = mfma(WtFrag, xFrag): lane stores node = tile*16+ln, channels ch0..ch0+3
// (mapping verified in round 7). No LDS, no per-lane bounds checks.
// ---------------------------------------------------------------------------
__global__ __launch_bounds__(256) void qkv_mfma(
    const float* __restrict__ x, const f16* __restrict__ Wt,
    const float* __restrict__ bq, const float* __restrict__ bk,
    const float* __restrict__ bv,
    u16* __restrict__ Q, u16* __restrict__ K, u16* __restrict__ V)
{
    const int wave = threadIdx.x >> 6;
    const int lane = threadIdx.x & 63;
    const int g = lane >> 4, ln = lane & 15;
    const int gw = blockIdx.x * 4 + wave;     // 0..3127
    const int ctg = gw & 7;                   // ct-group: cts ctg*3..ctg*3+2
    const int tileg = gw >> 3;                // 0..390

    const int ctA = ctg * 3, ctB = ctA + 1, ctC = ctA + 2;

    // hoisted Wt fragments (48 VGPR)
    f16x8 wtA[4], wtB[4], wtC[4];
    #pragma unroll
    for (int ks = 0; ks < 4; ks++) {
        wtA[ks] = *reinterpret_cast<const f16x8*>(Wt + (size_t)(ctA * 16 + ln) * 128 + ks * 32 + g * 8);
        wtB[ks] = *reinterpret_cast<const f16x8*>(Wt + (size_t)(ctB * 16 + ln) * 128 + ks * 32 + g * 8);
        wtC[ks] = *reinterpret_cast<const f16x8*>(Wt + (size_t)(ctC * 16 + ln) * 128 + ks * 32 + g * 8);
    }

    const int mtA = ctA >> 3, mtB = ctB >> 3, mtC = ctC >> 3;
    const int chA = (ctA & 7) * 16 + g * 4;
    const int chB = (ctB & 7) * 16 + g * 4;
    const int chC = (ctC & 7) * 16 + g * 4;
    u16* opA = (mtA == 0) ? Q : (mtA == 1) ? K : V;
    u16* opB = (mtB == 0) ? Q : (mtB == 1) ? K : V;
    u16* opC = (mtC == 0) ? Q : (mtC == 1) ? K : V;
    const float* bpA = (mtA == 0) ? bq : (mtA == 1) ? bk : bv;
    const float* bpB = (mtB == 0) ? bq : (mtB == 1) ? bk : bv;
    const float* bpC = (mtC == 0) ? bq : (mtC == 1) ? bk : bv;
    const float4 biasA = *reinterpret_cast<const float4*>(bpA + chA);
    const float4 biasB = *reinterpret_cast<const float4*>(bpB + chB);
    const float4 biasC = *reinterpret_cast<const float4*>(bpC + chC);

    const int tile0 = tileg * 8;
    // lane's x row base for tile t: (tile0+t)*16 + ln; 32 float4 per row
    const float4* xr = reinterpret_cast<const float4*>(x) + ((size_t)tile0 * 16 + ln) * 32;

    float4 f0, f1, f2, f3, f4, f5, f6, f7;
    f16x8 Bx0, Bx1, Bx2, Bx3;

#define LOADX(T) do { const float4* p_ = xr + (size_t)(T) * 512 + g * 2;  \
        f0 = p_[0];  f1 = p_[1];  f2 = p_[8];  f3 = p_[9];                \
        f4 = p_[16]; f5 = p_[17]; f6 = p_[24]; f7 = p_[25]; } while (0)
#define CVTX do { Bx0 = cvt2(f0, f1); Bx1 = cvt2(f2, f3);                 \
                  Bx2 = cvt2(f4, f5); Bx3 = cvt2(f6, f7); } while (0)

    LOADX(0);
    CVTX;

    #pragma unroll
    for (int t = 0; t < 8; t++) {
        const bool nlive = (t < 7) && (tile0 + t + 1 < TILES);
        if (nlive) LOADX(t + 1);

        f32x4 aA = {0.f,0.f,0.f,0.f}, aB = {0.f,0.f,0.f,0.f}, aC = {0.f,0.f,0.f,0.f};
        aA = __builtin_amdgcn_mfma_f32_16x16x32_f16(wtA[0], Bx0, aA, 0, 0, 0);
        aB = __builtin_amdgcn_mfma_f32_16x16x32_f16(wtB[0], Bx0, aB, 0, 0, 0);
        aC = __builtin_amdgcn_mfma_f32_16x16x32_f16(wtC[0], Bx0, aC, 0, 0, 0);
        aA = __builtin_amdgcn_mfma_f32_16x16x32_f16(wtA[1], Bx1, aA, 0, 0, 0);
        aB = __builtin_amdgcn_mfma_f32_16x16x32_f16(wtB[1], Bx1, aB, 0, 0, 0);
        aC = __builtin_amdgcn_mfma_f32_16x16x32_f16(wtC[1], Bx1, aC, 0, 0, 0);
        aA = __builtin_amdgcn_mfma_f32_16x16x32_f16(wtA[2], Bx2, aA, 0, 0, 0);
        aB = __builtin_amdgcn_mfma_f32_16x16x32_f16(wtB[2], Bx2, aB, 0, 0, 0);
        aC = __builtin_amdgcn_mfma_f32_16x16x32_f16(wtC[2], Bx2, aC, 0, 0, 0);
        aA = __builtin_amdgcn_mfma_f32_16x16x32_f16(wtA[3], Bx3, aA, 0, 0, 0);
        aB = __builtin_amdgcn_mfma_f32_16x16x32_f16(wtB[3], Bx3, aB, 0, 0, 0);
        aC = __builtin_amdgcn_mfma_f32_16x16x32_f16(wtC[3], Bx3, aC, 0, 0, 0);

        if (tile0 + t < TILES) {
            const size_t node = (size_t)(tile0 + t) * 16 + ln;
            ushort4 o;
            o.x = f2h(aA[0] + biasA.x); o.y = f2h(aA[1] + biasA.y);
            o.z = f2h(aA[2] + biasA.z); o.w = f2h(aA[3] + biasA.w);
            *reinterpret_cast<ushort4*>(opA + node * HDIM + chA) = o;
            o.x = f2h(aB[0] + biasB.x); o.y = f2h(aB[1] + biasB.y);
            o.z = f2h(aB[2] + biasB.z); o.w = f2h(aB[3] + biasB.w);
            *reinterpret_cast<ushort4*>(opB + node * HDIM + chB) = o;
            o.x = f2h(aC[0] + biasC.x); o.y = f2h(aC[1] + biasC.y);
            o.z = f2h(aC[2] + biasC.z); o.w = f2h(aC[3] + biasC.w);
            *reinterpret_cast<ushort4*>(opC + node * HDIM + chC) = o;
        }
        if (nlive) CVTX;
    }
#undef LOADX
#undef CVTX
}

// ---------------------------------------------------------------------------
// CSR scan: per-block sums, then fused global scan + local scan
// ---------------------------------------------------------------------------
__global__ __launch_bounds__(256) void scan_a(
    const int* __restrict__ counts, int* __restrict__ blocksum)
{
    __shared__ int s[256];
    int t = threadIdx.x, b = blockIdx.x;
    int i = b * 256 + t;
    int v = (i < NN) ? counts[i] : 0;
    s[t] = v; __syncthreads();
    for (int d = 128; d > 0; d >>= 1) {
        if (t < d) s[t] += s[t + d];
        __syncthreads();
    }
    if (t == 0) blocksum[b] = s[0];
}

__global__ __launch_bounds__(256) void scan_bc(
    const int* __restrict__ counts, const int* __restrict__ blocksum,
    int* __restrict__ offs, int* __restrict__ cursor)
{
    __shared__ int bs[256];
    __shared__ int s[256];
    int t = threadIdx.x, b = blockIdx.x;
    const int nb = ZEROB;                      // 196
    int bv = (t < nb) ? blocksum[t] : 0;
    bs[t] = bv; __syncthreads();
    s[t] = bs[t]; __syncthreads();
    for (int d = 1; d < 256; d <<= 1) {
        int add = (t >= d) ? s[t - d] : 0;
        __syncthreads();
        s[t] += add;
        __syncthreads();
    }
    const int blockoff = s[b] - bs[b];
    __syncthreads();

    int i = b * 256 + t;
    int v = (i < NN) ? counts[i] : 0;
    s[t] = v; __syncthreads();
    for (int d = 1; d < 256; d <<= 1) {
        int add = (t >= d) ? s[t - d] : 0;
        __syncthreads();
        s[t] += add;
        __syncthreads();
    }
    if (i < NN) {
        int off = blockoff + s[t] - v;
        offs[i] = off;
        cursor[i] = off;
    }
    if (b == 0 && t == 0) offs[NN] = ETOT;
}

__global__ __launch_bounds__(256) void scatter_k(
    const int* __restrict__ esrc, const int* __restrict__ edst,
    const int* __restrict__ eattr,
    int* __restrict__ cursor, int* __restrict__ sorted)
{
    int t = blockIdx.x * 256 + threadIdx.x;
    if (t >= ETOT) return;
    int dest = edst[t];
    int attr = (t < EREAL) ? eattr[t] : 16;    // 16 = fake-edge row
    int pos = atomicAdd(&cursor[dest], 1);
    sorted[pos] = esrc[t] | (attr << 20);
}

// ---------------------------------------------------------------------------
// gather-reduce, unroll-by-4. One wave per dest node; lane covers 2 elems.
// ---------------------------------------------------------------------------
__global__ __launch_bounds__(256) void gather_reduce(
    const u16* __restrict__ Q, const u16* __restrict__ K, const u16* __restrict__ V,
    const float* __restrict__ Et, const float* __restrict__ Eft,
    const int* __restrict__ offs, const int* __restrict__ sorted,
    float* __restrict__ out)
{
    const int lane = threadIdx.x & 63;
    int n = blockIdx.x * 4 + (threadIdx.x >> 6);
    n = __builtin_amdgcn_readfirstlane(n);

    const unsigned int* Qp = reinterpret_cast<const unsigned int*>(Q);
    const unsigned int* Kp = reinterpret_cast<const unsigned int*>(K);
    const unsigned int* Vp = reinterpret_cast<const unsigned int*>(V);

    unsigned int qu = Qp[(size_t)n * 64 + lane];
    const float q0 = h2f(qu & 0xffffu) * 0.25f, q1 = h2f(qu >> 16) * 0.25f;

    float accx = 0.f, accy = 0.f, zacc = 0.f;
    int i = offs[n];
    const int end = offs[n + 1];

    for (; i + 3 < end; i += 4) {
        int rec0 = sorted[i],     rec1 = sorted[i + 1];
        int rec2 = sorted[i + 2], rec3 = sorted[i + 3];
        int s0 = rec0 & 0xFFFFF, s1 = rec1 & 0xFFFFF;
        int s2 = rec2 & 0xFFFFF, s3 = rec3 & 0xFFFFF;
        unsigned int ku0 = Kp[(size_t)s0 * 64 + lane];
        unsigned int ku1 = Kp[(size_t)s1 * 64 + lane];
        unsigned int ku2 = Kp[(size_t)s2 * 64 + lane];
        unsigned int ku3 = Kp[(size_t)s3 * 64 + lane];
        unsigned int vu0 = Vp[(size_t)s0 * 64 + lane];
        unsigned int vu1 = Vp[(size_t)s1 * 64 + lane];
        unsigned int vu2 = Vp[(size_t)s2 * 64 + lane];
        unsigned int vu3 = Vp[(size_t)s3 * 64 + lane];
        int a0 = rec0 >> 20, a1 = rec1 >> 20, a2 = rec2 >> 20, a3 = rec3 >> 20;
        float2 e0 = *reinterpret_cast<const float2*>(((a0 < 16) ? (Et + a0 * HDIM) : Eft) + 2 * lane);
        float2 e1 = *reinterpret_cast<const float2*>(((a1 < 16) ? (Et + a1 * HDIM) : Eft) + 2 * lane);
        float2 e2 = *reinterpret_cast<const float2*>(((a2 < 16) ? (Et + a2 * HDIM) : Eft) + 2 * lane);
        float2 e3 = *reinterpret_cast<const float2*>(((a3 < 16) ? (Et + a3 * HDIM) : Eft) + 2 * lane);

        float p0 = h2f(ku0 & 0xffffu) * q0 * e0.x + h2f(ku0 >> 16) * q1 * e0.y;
        float p1 = h2f(ku1 & 0xffffu) * q0 * e1.x + h2f(ku1 >> 16) * q1 * e1.y;
        float p2 = h2f(ku2 & 0xffffu) * q0 * e2.x + h2f(ku2 >> 16) * q1 * e2.y;
        float p3 = h2f(ku3 & 0xffffu) * q0 * e3.x + h2f(ku3 >> 16) * q1 * e3.y;
        p0 += __shfl_xor(p0, 1); p1 += __shfl_xor(p1, 1);
        p2 += __shfl_xor(p2, 1); p3 += __shfl_xor(p3, 1);
        p0 += __shfl_xor(p0, 2); p1 += __shfl_xor(p1, 2);
        p2 += __shfl_xor(p2, 2); p3 += __shfl_xor(p3, 2);
        p0 += __shfl_xor(p0, 4); p1 += __shfl_xor(p1, 4);
        p2 += __shfl_xor(p2, 4); p3 += __shfl_xor(p3, 4);
        float c0 = __expf(fminf(fmaxf(p0, -5.f), 5.f));
        float c1 = __expf(fminf(fmaxf(p1, -5.f), 5.f));
        float c2 = __expf(fminf(fmaxf(p2, -5.f), 5.f));
        float c3 = __expf(fminf(fmaxf(p3, -5.f), 5.f));

        accx += h2f(vu0 & 0xffffu) * c0 + h2f(vu1 & 0xffffu) * c1
              + h2f(vu2 & 0xffffu) * c2 + h2f(vu3 & 0xffffu) * c3;
        accy += h2f(vu0 >> 16) * c0 + h2f(vu1 >> 16) * c1
              + h2f(vu2 >> 16) * c2 + h2f(vu3 >> 16) * c3;
        zacc += c0 + c1 + c2 + c3;
    }
    for (; i < end; ++i) {
        int rec  = sorted[i];
        int src  = rec & 0xFFFFF, attr = rec >> 20;
        unsigned int ku = Kp[(size_t)src * 64 + lane];
        unsigned int vu = Vp[(size_t)src * 64 + lane];
        const float* ep = (attr < 16) ? (Et + attr * HDIM) : Eft;
        float2 e = *reinterpret_cast<const float2*>(ep + 2 * lane);
        float p = h2f(ku & 0xffffu) * q0 * e.x + h2f(ku >> 16) * q1 * e.y;
        p += __shfl_xor(p, 1);
        p += __shfl_xor(p, 2);
        p += __shfl_xor(p, 4);
        float sc = __expf(fminf(fmaxf(p, -5.f), 5.f));
        accx += h2f(vu & 0xffffu) * sc;  accy += h2f(vu >> 16) * sc;  zacc += sc;
    }

    float inv = 1.f / (zacc + 1e-6f);
    float2 o; o.x = accx * inv; o.y = accy * inv;
    *reinterpret_cast<float2*>(out + (size_t)n * HDIM + 2 * lane) = o;
}

extern "C" void kernel_launch(void* const* d_in, const int* in_sizes, int n_in,
                              void* d_out, int out_size, void* d_ws, size_t ws_size,
                              hipStream_t stream)
{
    const float* x   = (const float*)d_in[0];
    const float* Wq  = (const float*)d_in[1];
    const float* bq  = (const float*)d_in[2];
    const float* Wk  = (const float*)d_in[3];
    const float* bk  = (const float*)d_in[4];
    const float* Wv  = (const float*)d_in[5];
    const float* bv  = (const float*)d_in[6];
    const float* Et  = (const float*)d_in[7];
    const float* Eft = (const float*)d_in[8];
    const int* eattr = (const int*)d_in[9];
    const int* esrc  = (const int*)d_in[11];
    const int* edst  = (const int*)d_in[12];

    char* ws = (char*)d_ws;
    const size_t qkv_bytes = (size_t)NN * HDIM * sizeof(u16);       // 12,800,000
    u16* Q = (u16*)(ws);
    u16* K = (u16*)(ws + qkv_bytes);
    u16* V = (u16*)(ws + 2 * qkv_bytes);
    size_t off = 3 * qkv_bytes;
    int* offs      = (int*)(ws + off); off += ((NN + 1) * 4 + 12) & ~15ull;
    int* cursor    = (int*)(ws + off); off += (size_t)NN * 4;
    int* counts    = (int*)(ws + off); off += (size_t)NN * 4;
    int* blocksum  = (int*)(ws + off); off += 1024;
    int* sorted    = (int*)(ws + off); off += (size_t)ETOT * 4;     // 2.6 MB
    f16* Wt        = (f16*)(ws + off);                              // 96 KB

    hipMemsetAsync(counts, 0, (size_t)NN * 4, stream);
    fused_init<<<CVTB + HISTB, 256, 0, stream>>>(Wq, Wk, Wv, Wt, edst, counts);
    qkv_mfma<<<QKVB, 256, 0, stream>>>(x, Wt, bq, bk, bv, Q, K, V);
    scan_a<<<ZEROB, 256, 0, stream>>>(counts, blocksum);
    scan_bc<<<ZEROB, 256, 0, stream>>>(counts, blocksum, offs, cursor);
    scatter_k<<<HISTB, 256, 0, stream>>>(esrc, edst, eattr, cursor, sorted);
    gather_reduce<<<NN / 4, 256, 0, stream>>>(Q, K, V, Et, Eft, offs, sorted, (float*)d_out);
}